// Round 1
// baseline (335.956 us; speedup 1.0000x reference)
//
#include <hip/hip_runtime.h>
#include <stdint.h>

typedef __attribute__((ext_vector_type(8))) short short8;
typedef __attribute__((ext_vector_type(8))) __bf16 bf16x8v;
typedef __attribute__((ext_vector_type(4))) float f32x4;

#define GLOBAL_AS __attribute__((address_space(1)))
#define LDS_AS __attribute__((address_space(3)))

__device__ __forceinline__ void gl2lds16(const void* g, void* l) {
  __builtin_amdgcn_global_load_lds((const GLOBAL_AS void*)g, (LDS_AS void*)l, 16, 0, 0);
}

__device__ __forceinline__ unsigned short f2bf(float x) {
  unsigned int u = __builtin_bit_cast(unsigned int, x);
  return (unsigned short)((u + 0x7fffu + ((u >> 16) & 1u)) >> 16);
}

__device__ __forceinline__ short8 ldv8(const unsigned short* p) {
  return *(const short8*)p;
}

// --- MFMA wrapper: SFINAE-hedged against builtin operand type (short8 vs v8bf16) ---
template <typename T>
__device__ __forceinline__ auto mfma_impl(T a, T b, f32x4 c, int)
    -> decltype(__builtin_amdgcn_mfma_f32_16x16x32_bf16(a, b, c, 0, 0, 0)) {
  return __builtin_amdgcn_mfma_f32_16x16x32_bf16(a, b, c, 0, 0, 0);
}
template <typename T>
__device__ __forceinline__ f32x4 mfma_impl(T a, T b, f32x4 c, long) {
  bf16x8v aa = __builtin_bit_cast(bf16x8v, a);
  bf16x8v bb = __builtin_bit_cast(bf16x8v, b);
  return __builtin_amdgcn_mfma_f32_16x16x32_bf16(aa, bb, c, 0, 0, 0);
}
__device__ __forceinline__ f32x4 mfma16(short8 a, short8 b, f32x4 c) {
  return mfma_impl(a, b, c, 0);
}

// ---------------- cast fp32 -> bf16 (vectorized) ----------------
__global__ __launch_bounds__(256) void cast_bf16_kernel(const float* __restrict__ X,
                                                        unsigned short* __restrict__ Y,
                                                        int n4) {
  int i = blockIdx.x * 256 + threadIdx.x;
  if (i >= n4) return;
  const float4 v = ((const float4*)X)[i];
  unsigned long long pk = (unsigned long long)f2bf(v.x)
                        | ((unsigned long long)f2bf(v.y) << 16)
                        | ((unsigned long long)f2bf(v.z) << 32)
                        | ((unsigned long long)f2bf(v.w) << 48);
  ((unsigned long long*)Y)[i] = pk;
}

// ---------------- transpose + cast: W[K][N] fp32 -> Wt[N][K] bf16 ----------------
__global__ __launch_bounds__(256) void transpose_cast_kernel(const float* __restrict__ W,
                                                             unsigned short* __restrict__ Wt,
                                                             int Kd, int Nd) {
  __shared__ unsigned short tile[32][33];
  const int n0 = blockIdx.x * 32, k0 = blockIdx.y * 32;
  const int tx = threadIdx.x & 31, ty = threadIdx.x >> 5;  // 32x8
  #pragma unroll
  for (int i = 0; i < 4; ++i)
    tile[ty + i * 8][tx] = f2bf(W[(long)(k0 + ty + i * 8) * Nd + n0 + tx]);
  __syncthreads();
  #pragma unroll
  for (int i = 0; i < 4; ++i)
    Wt[(long)(n0 + ty + i * 8) * Kd + k0 + tx] = tile[tx][ty + i * 8];
}

// ---------------- GEMM: C[M,N] = A[M,K] @ Wt[N,K]^T + bias ----------------
// MODE 0: scatter into Q[B,H,S,64], K[B,H,S,64], Vt[B,H,64,S] (bf16)
// MODE 1: write fp32 [M][N]
template <int MODE>
__global__ __launch_bounds__(256) void gemm_kernel(
    const unsigned short* __restrict__ A,   // [M][K] bf16
    const unsigned short* __restrict__ Wt,  // [N][K] bf16
    const float* __restrict__ bias,         // [N]
    float* __restrict__ Cout,               // MODE1
    unsigned short* __restrict__ Qb,
    unsigned short* __restrict__ Kb,
    unsigned short* __restrict__ Vt,
    int M, int N, int K) {
  __shared__ __align__(16) unsigned short Asm[128 * 32];
  __shared__ __align__(16) unsigned short Bsm[128 * 32];
  const int tid = threadIdx.x;
  const int w = tid >> 6, l = tid & 63;
  const int m0 = blockIdx.y * 128, n0 = blockIdx.x * 128;
  const int wr = (w >> 1) * 64, wc = (w & 1) * 64;
  const int laneRow = l & 15, laneG = l >> 4;

  const f32x4 z4 = {0.f, 0.f, 0.f, 0.f};
  f32x4 acc[4][4];
  #pragma unroll
  for (int m = 0; m < 4; ++m)
    #pragma unroll
    for (int n = 0; n < 4; ++n) acc[m][n] = z4;

  const int srow = tid >> 2;
  const int scol = (tid & 3) * 8;
  const unsigned short* Ag = A + (long)(m0 + srow) * K + scol;
  const unsigned short* Bg = Wt + (long)(n0 + srow) * K + scol;
  unsigned short* AsmW = Asm + w * 512;
  unsigned short* BsmW = Bsm + w * 512;

  const int aoff = (wr + laneRow) * 32 + laneG * 8;
  const int boff = (wc + laneRow) * 32 + laneG * 8;

  for (int kt = 0; kt < K; kt += 32) {
    gl2lds16(Ag + kt, AsmW);
    gl2lds16(Ag + (long)64 * K + kt, AsmW + 2048);
    gl2lds16(Bg + kt, BsmW);
    gl2lds16(Bg + (long)64 * K + kt, BsmW + 2048);
    __syncthreads();
    short8 af[4], bfr[4];
    #pragma unroll
    for (int m = 0; m < 4; ++m) af[m] = ldv8(Asm + aoff + m * 512);
    #pragma unroll
    for (int n = 0; n < 4; ++n) bfr[n] = ldv8(Bsm + boff + n * 512);
    #pragma unroll
    for (int m = 0; m < 4; ++m)
      #pragma unroll
      for (int n = 0; n < 4; ++n)
        acc[m][n] = mfma16(af[m], bfr[n], acc[m][n]);
    __syncthreads();
  }

  #pragma unroll
  for (int m = 0; m < 4; ++m) {
    const int row_base = m0 + wr + m * 16 + laneG * 4;
    #pragma unroll
    for (int n = 0; n < 4; ++n) {
      const int col = n0 + wc + n * 16 + laneRow;
      const float bv = bias[col];
      float v0 = acc[m][n][0] + bv;
      float v1 = acc[m][n][1] + bv;
      float v2 = acc[m][n][2] + bv;
      float v3 = acc[m][n][3] + bv;
      if (MODE == 1) {
        Cout[(long)(row_base + 0) * N + col] = v0;
        Cout[(long)(row_base + 1) * N + col] = v1;
        Cout[(long)(row_base + 2) * N + col] = v2;
        Cout[(long)(row_base + 3) * N + col] = v3;
      } else {
        const int which = col >> 10;
        const int d = col & 1023;
        const int h = d >> 6, e = d & 63;
        const int bb = row_base >> 11, s = row_base & 2047;
        if (which == 2) {
          // V transposed: Vt[(bb*16+h)*64 + e][s..s+3] — 4 consecutive tokens, 8B store
          unsigned long long pk = (unsigned long long)f2bf(v0)
                                | ((unsigned long long)f2bf(v1) << 16)
                                | ((unsigned long long)f2bf(v2) << 32)
                                | ((unsigned long long)f2bf(v3) << 48);
          *(unsigned long long*)(Vt + ((long)((bb * 16 + h) * 64 + e)) * 2048 + s) = pk;
        } else {
          unsigned short* T = (which == 0) ? Qb : Kb;
          long base = ((long)(bb * 16 + h) * 2048 + s) * 64 + e;
          T[base] = f2bf(v0);
          T[base + 64] = f2bf(v1);
          T[base + 128] = f2bf(v2);
          T[base + 192] = f2bf(v3);
        }
      }
    }
  }
}

// ---------------- flash attention (causal), bf16 MFMA ----------------
// grid: (S/64, B*H). block 256 = 4 waves, each wave owns 16 q-rows.
__global__ __launch_bounds__(256) void attn_kernel(
    const unsigned short* __restrict__ Qb,   // [B*H][2048][64]
    const unsigned short* __restrict__ Kb,   // [B*H][2048][64]
    const unsigned short* __restrict__ Vt,   // [B*H][64][2048]
    unsigned short* __restrict__ Ao) {       // [B*2048][1024]
  __shared__ __align__(16) unsigned short Ksm[64 * 64];
  __shared__ __align__(16) unsigned short Vsm[64 * 64];
  __shared__ __align__(16) unsigned short Psm[4][16][72];  // +8 pad vs bank conflicts

  const int tid = threadIdx.x;
  const int w = tid >> 6, l = tid & 63;
  const int x = blockIdx.x, y = blockIdx.y;
  const int laneRow = l & 15, g = l >> 4;
  const unsigned short* Qh = Qb + (long)y * (2048 * 64);
  const unsigned short* Kh = Kb + (long)y * (2048 * 64);
  const unsigned short* Vh = Vt + (long)y * (64 * 2048);
  const int q0 = x * 64 + w * 16;

  short8 qf[2];
  qf[0] = ldv8(Qh + (q0 + laneRow) * 64 + g * 8);
  qf[1] = ldv8(Qh + (q0 + laneRow) * 64 + 32 + g * 8);

  float mr[4] = {-1e30f, -1e30f, -1e30f, -1e30f};
  float lr[4] = {0.f, 0.f, 0.f, 0.f};
  const f32x4 z4 = {0.f, 0.f, 0.f, 0.f};
  f32x4 o[4];
  #pragma unroll
  for (int i = 0; i < 4; ++i) o[i] = z4;

  // staging: slot = issue*256+tid; row = slot>>3, c16 = slot&7, XOR-swizzled source
  const int srow = tid >> 3;   // 0..31 (+32 for issue 1)
  const int sc16 = tid & 7;
  const int sxor = (sc16 ^ (srow & 7)) * 8;

  for (int kt = 0; kt <= x; ++kt) {
    __syncthreads();
    const unsigned short* Kg = Kh + (long)kt * (64 * 64);
    const unsigned short* Vg = Vh + kt * 64;
    gl2lds16(Kg + srow * 64 + sxor, Ksm + w * 512);
    gl2lds16(Kg + (srow + 32) * 64 + sxor, Ksm + 2048 + w * 512);
    gl2lds16(Vg + (long)srow * 2048 + sxor, Vsm + w * 512);
    gl2lds16(Vg + (long)(srow + 32) * 2048 + sxor, Vsm + 2048 + w * 512);
    __syncthreads();

    // S = Q K^T  (16q x 64k per wave)
    f32x4 sc[4];
    #pragma unroll
    for (int n = 0; n < 4; ++n) {
      const int krow = n * 16 + laneRow;
      f32x4 a = z4;
      short8 b0 = ldv8(Ksm + krow * 64 + ((g ^ (krow & 7)) * 8));
      short8 b1 = ldv8(Ksm + krow * 64 + (((g + 4) ^ (krow & 7)) * 8));
      a = mfma16(qf[0], b0, a);
      a = mfma16(qf[1], b1, a);
      sc[n] = a;
    }

    // scale + causal mask
    #pragma unroll
    for (int n = 0; n < 4; ++n) {
      const int key = kt * 64 + n * 16 + laneRow;
      #pragma unroll
      for (int r = 0; r < 4; ++r) {
        float v = sc[n][r] * 0.125f;
        if (key > q0 + g * 4 + r) v = -10000.0f;
        sc[n][r] = v;
      }
    }

    // online softmax (rows live in 16-lane groups)
    float pm[4];
    #pragma unroll
    for (int r = 0; r < 4; ++r) {
      float v = fmaxf(fmaxf(sc[0][r], sc[1][r]), fmaxf(sc[2][r], sc[3][r]));
      v = fmaxf(v, __shfl_xor(v, 1));
      v = fmaxf(v, __shfl_xor(v, 2));
      v = fmaxf(v, __shfl_xor(v, 4));
      v = fmaxf(v, __shfl_xor(v, 8));
      pm[r] = v;
    }
    float so[4];
    #pragma unroll
    for (int r = 0; r < 4; ++r) {
      float mn = fmaxf(mr[r], pm[r]);
      so[r] = __expf(mr[r] - mn);
      mr[r] = mn;
    }
    float rs[4] = {0.f, 0.f, 0.f, 0.f};
    #pragma unroll
    for (int n = 0; n < 4; ++n)
      #pragma unroll
      for (int r = 0; r < 4; ++r) {
        float p = __expf(sc[n][r] - mr[r]);
        sc[n][r] = p;
        rs[r] += p;
      }
    #pragma unroll
    for (int r = 0; r < 4; ++r) {
      float v = rs[r];
      v += __shfl_xor(v, 1);
      v += __shfl_xor(v, 2);
      v += __shfl_xor(v, 4);
      v += __shfl_xor(v, 8);
      lr[r] = lr[r] * so[r] + v;
    }
    #pragma unroll
    for (int n2 = 0; n2 < 4; ++n2) {
      o[n2][0] *= so[0];
      o[n2][1] *= so[1];
      o[n2][2] *= so[2];
      o[n2][3] *= so[3];
    }

    // P -> LDS (per-wave, padded)
    #pragma unroll
    for (int n = 0; n < 4; ++n)
      #pragma unroll
      for (int r = 0; r < 4; ++r)
        Psm[w][g * 4 + r][n * 16 + laneRow] = f2bf(sc[n][r]);
    asm volatile("s_waitcnt lgkmcnt(0)" ::: "memory");

    // O += P V
    #pragma unroll
    for (int kk = 0; kk < 2; ++kk) {
      short8 pf = ldv8(&Psm[w][laneRow][kk * 32 + g * 8]);
      #pragma unroll
      for (int n2 = 0; n2 < 4; ++n2) {
        const int vrow = n2 * 16 + laneRow;
        short8 vf = ldv8(Vsm + vrow * 64 + (((g + kk * 4) ^ (vrow & 7)) * 8));
        o[n2] = mfma16(pf, vf, o[n2]);
      }
    }
  }

  const int b = y >> 4, h = y & 15;
  #pragma unroll
  for (int n2 = 0; n2 < 4; ++n2) {
    #pragma unroll
    for (int r = 0; r < 4; ++r) {
      float v = o[n2][r] / lr[r];
      long row = (long)b * 2048 + q0 + g * 4 + r;
      Ao[row * 1024 + h * 64 + n2 * 16 + laneRow] = f2bf(v);
    }
  }
}

// ---------------- launch ----------------
extern "C" void kernel_launch(void* const* d_in, const int* in_sizes, int n_in,
                              void* d_out, int out_size, void* d_ws, size_t ws_size,
                              hipStream_t stream) {
  const float* hs = (const float*)d_in[0];      // [4,2048,1024]
  const float* W_attn = (const float*)d_in[1];  // [1024,3072]
  const float* b_attn = (const float*)d_in[2];  // [3072]
  const float* W_proj = (const float*)d_in[3];  // [1024,1024]
  const float* b_proj = (const float*)d_in[4];  // [1024]
  float* out = (float*)d_out;

  const size_t SZ_HS = 16777216;  // 8192*1024*2
  const size_t SZ_WA = 6291456;   // 3072*1024*2
  const size_t SZ_WP = 2097152;   // 1024*1024*2
  const size_t SZ_T = 16777216;   // Q / K / Vt / Ao each
  if (ws_size < SZ_HS + SZ_WA + SZ_WP + 4 * SZ_T) return;

  char* p = (char*)d_ws;
  unsigned short* hs_bf = (unsigned short*)p; p += SZ_HS;
  unsigned short* WtA = (unsigned short*)p;   p += SZ_WA;
  unsigned short* WtP = (unsigned short*)p;   p += SZ_WP;
  unsigned short* Qb = (unsigned short*)p;    p += SZ_T;
  unsigned short* Kb = (unsigned short*)p;    p += SZ_T;
  unsigned short* Vt = (unsigned short*)p;    p += SZ_T;
  unsigned short* Ao = (unsigned short*)p;    p += SZ_T;

  cast_bf16_kernel<<<8192, 256, 0, stream>>>(hs, hs_bf, 8192 * 1024 / 4);
  transpose_cast_kernel<<<dim3(96, 32), 256, 0, stream>>>(W_attn, WtA, 1024, 3072);
  transpose_cast_kernel<<<dim3(32, 32), 256, 0, stream>>>(W_proj, WtP, 1024, 1024);
  gemm_kernel<0><<<dim3(24, 64), 256, 0, stream>>>(hs_bf, WtA, b_attn, nullptr, Qb, Kb, Vt,
                                                   8192, 3072, 1024);
  attn_kernel<<<dim3(32, 64), 256, 0, stream>>>(Qb, Kb, Vt, Ao);
  gemm_kernel<1><<<dim3(8, 64), 256, 0, stream>>>(Ao, WtP, b_proj, out, nullptr, nullptr, nullptr,
                                                  8192, 1024, 1024);
}

// Round 3
// 256.343 us; speedup vs baseline: 1.3106x; 1.3106x over previous
//
#include <hip/hip_runtime.h>
#include <stdint.h>

typedef __attribute__((ext_vector_type(8))) short short8;
typedef __attribute__((ext_vector_type(8))) __bf16 bf16x8v;
typedef __attribute__((ext_vector_type(4))) float f32x4;

#define GLOBAL_AS __attribute__((address_space(1)))
#define LDS_AS __attribute__((address_space(3)))

__device__ __forceinline__ void gl2lds16(const void* g, void* l) {
  __builtin_amdgcn_global_load_lds((const GLOBAL_AS void*)g, (LDS_AS void*)l, 16, 0, 0);
}

__device__ __forceinline__ unsigned short f2bf(float x) {
  unsigned int u = __builtin_bit_cast(unsigned int, x);
  return (unsigned short)((u + 0x7fffu + ((u >> 16) & 1u)) >> 16);
}

__device__ __forceinline__ float bf2f(unsigned short u) {
  unsigned int v = (unsigned int)u << 16;
  return __builtin_bit_cast(float, v);
}

__device__ __forceinline__ short8 ldv8(const unsigned short* p) {
  return *(const short8*)p;
}

// --- MFMA wrapper: SFINAE-hedged against builtin operand type (short8 vs v8bf16) ---
template <typename T>
__device__ __forceinline__ auto mfma_impl(T a, T b, f32x4 c, int)
    -> decltype(__builtin_amdgcn_mfma_f32_16x16x32_bf16(a, b, c, 0, 0, 0)) {
  return __builtin_amdgcn_mfma_f32_16x16x32_bf16(a, b, c, 0, 0, 0);
}
template <typename T>
__device__ __forceinline__ f32x4 mfma_impl(T a, T b, f32x4 c, long) {
  bf16x8v aa = __builtin_bit_cast(bf16x8v, a);
  bf16x8v bb = __builtin_bit_cast(bf16x8v, b);
  return __builtin_amdgcn_mfma_f32_16x16x32_bf16(aa, bb, c, 0, 0, 0);
}
__device__ __forceinline__ f32x4 mfma16(short8 a, short8 b, f32x4 c) {
  return mfma_impl(a, b, c, 0);
}

// ---------------- cast fp32 -> bf16 (vectorized) ----------------
__global__ __launch_bounds__(256) void cast_bf16_kernel(const float* __restrict__ X,
                                                        unsigned short* __restrict__ Y,
                                                        int n4) {
  int i = blockIdx.x * 256 + threadIdx.x;
  if (i >= n4) return;
  const float4 v = ((const float4*)X)[i];
  unsigned long long pk = (unsigned long long)f2bf(v.x)
                        | ((unsigned long long)f2bf(v.y) << 16)
                        | ((unsigned long long)f2bf(v.z) << 32)
                        | ((unsigned long long)f2bf(v.w) << 48);
  ((unsigned long long*)Y)[i] = pk;
}

// ---------------- transpose + cast: W[K][N] fp32 -> Wt[N][K] bf16 ----------------
__global__ __launch_bounds__(256) void transpose_cast_kernel(const float* __restrict__ W,
                                                             unsigned short* __restrict__ Wt,
                                                             int Kd, int Nd) {
  __shared__ unsigned short tile[32][33];
  const int n0 = blockIdx.x * 32, k0 = blockIdx.y * 32;
  const int tx = threadIdx.x & 31, ty = threadIdx.x >> 5;  // 32x8
  #pragma unroll
  for (int i = 0; i < 4; ++i)
    tile[ty + i * 8][tx] = f2bf(W[(long)(k0 + ty + i * 8) * Nd + n0 + tx]);
  __syncthreads();
  #pragma unroll
  for (int i = 0; i < 4; ++i)
    Wt[(long)(n0 + ty + i * 8) * Kd + k0 + tx] = tile[tx][ty + i * 8];
}

// ---------------- GEMM: C[M,N] = A[M,K] @ Wt[N,K]^T + bias ----------------
template <int MODE>
__global__ __launch_bounds__(256) void gemm_kernel(
    const unsigned short* __restrict__ A,   // [M][K] bf16
    const unsigned short* __restrict__ Wt,  // [N][K] bf16
    const float* __restrict__ bias,         // [N]
    float* __restrict__ Cout,               // MODE1
    unsigned short* __restrict__ Qb,
    unsigned short* __restrict__ Kb,
    unsigned short* __restrict__ Vt,
    int M, int N, int K) {
  __shared__ __align__(16) unsigned short Asm[128 * 32];
  __shared__ __align__(16) unsigned short Bsm[128 * 32];
  const int tid = threadIdx.x;
  const int w = tid >> 6, l = tid & 63;
  const int m0 = blockIdx.y * 128, n0 = blockIdx.x * 128;
  const int wr = (w >> 1) * 64, wc = (w & 1) * 64;
  const int laneRow = l & 15, laneG = l >> 4;

  const f32x4 z4 = {0.f, 0.f, 0.f, 0.f};
  f32x4 acc[4][4];
  #pragma unroll
  for (int m = 0; m < 4; ++m)
    #pragma unroll
    for (int n = 0; n < 4; ++n) acc[m][n] = z4;

  const int srow = tid >> 2;
  const int scol = (tid & 3) * 8;
  const unsigned short* Ag = A + (long)(m0 + srow) * K + scol;
  const unsigned short* Bg = Wt + (long)(n0 + srow) * K + scol;
  unsigned short* AsmW = Asm + w * 512;
  unsigned short* BsmW = Bsm + w * 512;

  const int aoff = (wr + laneRow) * 32 + laneG * 8;
  const int boff = (wc + laneRow) * 32 + laneG * 8;

  for (int kt = 0; kt < K; kt += 32) {
    gl2lds16(Ag + kt, AsmW);
    gl2lds16(Ag + (long)64 * K + kt, AsmW + 2048);
    gl2lds16(Bg + kt, BsmW);
    gl2lds16(Bg + (long)64 * K + kt, BsmW + 2048);
    __syncthreads();
    short8 af[4], bfr[4];
    #pragma unroll
    for (int m = 0; m < 4; ++m) af[m] = ldv8(Asm + aoff + m * 512);
    #pragma unroll
    for (int n = 0; n < 4; ++n) bfr[n] = ldv8(Bsm + boff + n * 512);
    #pragma unroll
    for (int m = 0; m < 4; ++m)
      #pragma unroll
      for (int n = 0; n < 4; ++n)
        acc[m][n] = mfma16(af[m], bfr[n], acc[m][n]);
    __syncthreads();
  }

  #pragma unroll
  for (int m = 0; m < 4; ++m) {
    const int row_base = m0 + wr + m * 16 + laneG * 4;
    #pragma unroll
    for (int n = 0; n < 4; ++n) {
      const int col = n0 + wc + n * 16 + laneRow;
      const float bv = bias[col];
      float v0 = acc[m][n][0] + bv;
      float v1 = acc[m][n][1] + bv;
      float v2 = acc[m][n][2] + bv;
      float v3 = acc[m][n][3] + bv;
      if (MODE == 1) {
        Cout[(long)(row_base + 0) * N + col] = v0;
        Cout[(long)(row_base + 1) * N + col] = v1;
        Cout[(long)(row_base + 2) * N + col] = v2;
        Cout[(long)(row_base + 3) * N + col] = v3;
      } else {
        const int which = col >> 10;
        const int d = col & 1023;
        const int h = d >> 6, e = d & 63;
        const int bb = row_base >> 11, s = row_base & 2047;
        if (which == 2) {
          unsigned long long pk = (unsigned long long)f2bf(v0)
                                | ((unsigned long long)f2bf(v1) << 16)
                                | ((unsigned long long)f2bf(v2) << 32)
                                | ((unsigned long long)f2bf(v3) << 48);
          *(unsigned long long*)(Vt + ((long)((bb * 16 + h) * 64 + e)) * 2048 + s) = pk;
        } else {
          unsigned short* T = (which == 0) ? Qb : Kb;
          long base = ((long)(bb * 16 + h) * 2048 + s) * 64 + e;
          T[base] = f2bf(v0);
          T[base + 64] = f2bf(v1);
          T[base + 128] = f2bf(v2);
          T[base + 192] = f2bf(v3);
        }
      }
    }
  }
}

// ---------------- flash attention (causal), bf16 MFMA ----------------
// Load-balanced: block px handles q-tiles (px) and (31-px): 33 KV tiles total.
// grid: (16, B*H). block 256 = 4 waves, each wave owns 16 q-rows.
// Double-buffered K/V staging with prefetch; P via round-1-verified padded
// LDS buffer (Psm[w][q][key], scalar writes, ldv8 A-fragment reads).
__global__ __launch_bounds__(256) void attn_kernel(
    const unsigned short* __restrict__ Qb,   // [B*H][2048][64]
    const unsigned short* __restrict__ Kb,   // [B*H][2048][64]
    const unsigned short* __restrict__ Vt,   // [B*H][64][2048]
    unsigned short* __restrict__ Ao) {       // [B*2048][1024]
  __shared__ __align__(16) unsigned short Ksm[2][64 * 64];
  __shared__ __align__(16) unsigned short Vsm[2][64 * 64];
  __shared__ __align__(16) unsigned short Psm[4][16][72];  // +8 pad vs bank conflicts

  const int tid = threadIdx.x;
  const int w = tid >> 6, l = tid & 63;
  const int px = blockIdx.x, y = blockIdx.y;
  const int laneRow = l & 15, g = l >> 4;
  const unsigned short* Qh = Qb + (long)y * (2048 * 64);
  const unsigned short* Kh = Kb + (long)y * (2048 * 64);
  const unsigned short* Vh = Vt + (long)y * (64 * 2048);

  const int srow = tid >> 3;   // 0..31
  const int sc16 = tid & 7;
  const int sxor = (sc16 ^ (srow & 7)) * 8;
  const int b = y >> 4, h = y & 15;
  const f32x4 z4 = {0.f, 0.f, 0.f, 0.f};

  auto STAGE = [&](int buf, int kt) {
    const unsigned short* Kg = Kh + (long)kt * (64 * 64);
    const unsigned short* Vg = Vh + kt * 64;
    gl2lds16(Kg + srow * 64 + sxor, &Ksm[buf][w * 512]);
    gl2lds16(Kg + (srow + 32) * 64 + sxor, &Ksm[buf][2048 + w * 512]);
    gl2lds16(Vg + (long)srow * 2048 + sxor, &Vsm[buf][w * 512]);
    gl2lds16(Vg + (long)(srow + 32) * 2048 + sxor, &Vsm[buf][2048 + w * 512]);
  };

  for (int pass = 0; pass < 2; ++pass) {
    const int x = pass ? (31 - px) : px;
    const int q0 = x * 64 + w * 16;

    // Q fragments, pre-scaled by 1/sqrt(hd) (x0.125 is exact in bf16)
    short8 qf[2];
    {
      short8 r0 = ldv8(Qh + (q0 + laneRow) * 64 + g * 8);
      short8 r1 = ldv8(Qh + (q0 + laneRow) * 64 + 32 + g * 8);
      #pragma unroll
      for (int j = 0; j < 8; ++j) {
        qf[0][j] = (short)f2bf(bf2f((unsigned short)r0[j]) * 0.125f);
        qf[1][j] = (short)f2bf(bf2f((unsigned short)r1[j]) * 0.125f);
      }
    }

    float mr[4] = {-1e30f, -1e30f, -1e30f, -1e30f};
    float lr[4] = {0.f, 0.f, 0.f, 0.f};
    f32x4 o[4];
    #pragma unroll
    for (int i = 0; i < 4; ++i) o[i] = z4;

    int cur = 0;
    STAGE(0, 0);
    asm volatile("s_waitcnt vmcnt(0)" ::: "memory");
    __builtin_amdgcn_s_barrier();

    for (int kt = 0; kt <= x; ++kt) {
      if (kt < x) STAGE(cur ^ 1, kt + 1);  // prefetch next tile

      // S = Q K^T (pre-scaled)
      f32x4 sc[4];
      __builtin_amdgcn_s_setprio(1);
      #pragma unroll
      for (int n = 0; n < 4; ++n) {
        const int krow = n * 16 + laneRow;
        short8 b0 = ldv8(&Ksm[cur][krow * 64 + ((g ^ (krow & 7)) * 8)]);
        short8 b1 = ldv8(&Ksm[cur][krow * 64 + (((g + 4) ^ (krow & 7)) * 8)]);
        f32x4 a = mfma16(qf[0], b0, z4);
        sc[n] = mfma16(qf[1], b1, a);
      }
      __builtin_amdgcn_s_setprio(0);

      // causal mask: only the diagonal tile needs it
      if (kt == x) {
        #pragma unroll
        for (int n = 0; n < 4; ++n) {
          const int key = n * 16 + laneRow;
          #pragma unroll
          for (int r = 0; r < 4; ++r)
            if (key > w * 16 + g * 4 + r) sc[n][r] = -1e9f;
        }
      }

      // online softmax (rows live across 16-lane groups)
      float pm[4];
      #pragma unroll
      for (int r = 0; r < 4; ++r) {
        float v = fmaxf(fmaxf(sc[0][r], sc[1][r]), fmaxf(sc[2][r], sc[3][r]));
        v = fmaxf(v, __shfl_xor(v, 1));
        v = fmaxf(v, __shfl_xor(v, 2));
        v = fmaxf(v, __shfl_xor(v, 4));
        v = fmaxf(v, __shfl_xor(v, 8));
        pm[r] = v;
      }
      float so[4];
      #pragma unroll
      for (int r = 0; r < 4; ++r) {
        float mn = fmaxf(mr[r], pm[r]);
        so[r] = __expf(mr[r] - mn);
        mr[r] = mn;
      }
      float rs[4] = {0.f, 0.f, 0.f, 0.f};
      #pragma unroll
      for (int n = 0; n < 4; ++n)
        #pragma unroll
        for (int r = 0; r < 4; ++r) {
          float p = __expf(sc[n][r] - mr[r]);
          sc[n][r] = p;
          rs[r] += p;
        }
      #pragma unroll
      for (int r = 0; r < 4; ++r) {
        float v = rs[r];
        v += __shfl_xor(v, 1);
        v += __shfl_xor(v, 2);
        v += __shfl_xor(v, 4);
        v += __shfl_xor(v, 8);
        lr[r] = lr[r] * so[r] + v;
      }
      #pragma unroll
      for (int n2 = 0; n2 < 4; ++n2) {
        o[n2][0] *= so[0];
        o[n2][1] *= so[1];
        o[n2][2] *= so[2];
        o[n2][3] *= so[3];
      }

      // P -> LDS (per-wave, padded) — round-1-verified layout [q][key]
      #pragma unroll
      for (int n = 0; n < 4; ++n)
        #pragma unroll
        for (int r = 0; r < 4; ++r)
          Psm[w][g * 4 + r][n * 16 + laneRow] = f2bf(sc[n][r]);
      asm volatile("s_waitcnt lgkmcnt(0)" ::: "memory");

      // O += P V
      #pragma unroll
      for (int kk = 0; kk < 2; ++kk) {
        short8 pf = ldv8(&Psm[w][laneRow][kk * 32 + g * 8]);
        __builtin_amdgcn_s_setprio(1);
        #pragma unroll
        for (int n2 = 0; n2 < 4; ++n2) {
          const int vrow = n2 * 16 + laneRow;
          short8 vf = ldv8(&Vsm[cur][vrow * 64 + (((g + kk * 4) ^ (vrow & 7)) * 8)]);
          o[n2] = mfma16(pf, vf, o[n2]);
        }
        __builtin_amdgcn_s_setprio(0);
      }

      asm volatile("s_waitcnt vmcnt(0)" ::: "memory");
      __builtin_amdgcn_s_barrier();
      cur ^= 1;
    }

    // epilogue: O / l
    #pragma unroll
    for (int n2 = 0; n2 < 4; ++n2) {
      #pragma unroll
      for (int r = 0; r < 4; ++r) {
        float v = o[n2][r] / lr[r];
        long row = (long)b * 2048 + q0 + g * 4 + r;
        Ao[row * 1024 + h * 64 + n2 * 16 + laneRow] = f2bf(v);
      }
    }
  }
}

// ---------------- launch ----------------
extern "C" void kernel_launch(void* const* d_in, const int* in_sizes, int n_in,
                              void* d_out, int out_size, void* d_ws, size_t ws_size,
                              hipStream_t stream) {
  const float* hs = (const float*)d_in[0];      // [4,2048,1024]
  const float* W_attn = (const float*)d_in[1];  // [1024,3072]
  const float* b_attn = (const float*)d_in[2];  // [3072]
  const float* W_proj = (const float*)d_in[3];  // [1024,1024]
  const float* b_proj = (const float*)d_in[4];  // [1024]
  float* out = (float*)d_out;

  const size_t SZ_HS = 16777216;  // 8192*1024*2
  const size_t SZ_WA = 6291456;   // 3072*1024*2
  const size_t SZ_WP = 2097152;   // 1024*1024*2
  const size_t SZ_T = 16777216;   // Q / K / Vt / Ao each
  if (ws_size < SZ_HS + SZ_WA + SZ_WP + 4 * SZ_T) return;

  char* p = (char*)d_ws;
  unsigned short* hs_bf = (unsigned short*)p; p += SZ_HS;
  unsigned short* WtA = (unsigned short*)p;   p += SZ_WA;
  unsigned short* WtP = (unsigned short*)p;   p += SZ_WP;
  unsigned short* Qb = (unsigned short*)p;    p += SZ_T;
  unsigned short* Kb = (unsigned short*)p;    p += SZ_T;
  unsigned short* Vt = (unsigned short*)p;    p += SZ_T;
  unsigned short* Ao = (unsigned short*)p;    p += SZ_T;

  cast_bf16_kernel<<<8192, 256, 0, stream>>>(hs, hs_bf, 8192 * 1024 / 4);
  transpose_cast_kernel<<<dim3(96, 32), 256, 0, stream>>>(W_attn, WtA, 1024, 3072);
  transpose_cast_kernel<<<dim3(32, 32), 256, 0, stream>>>(W_proj, WtP, 1024, 1024);
  gemm_kernel<0><<<dim3(24, 64), 256, 0, stream>>>(hs_bf, WtA, b_attn, nullptr, Qb, Kb, Vt,
                                                   8192, 3072, 1024);
  attn_kernel<<<dim3(16, 64), 256, 0, stream>>>(Qb, Kb, Vt, Ao);
  gemm_kernel<1><<<dim3(8, 64), 256, 0, stream>>>(Ao, WtP, b_proj, out, nullptr, nullptr, nullptr,
                                                  8192, 1024, 1024);
}

// Round 4
// 224.969 us; speedup vs baseline: 1.4933x; 1.1395x over previous
//
#include <hip/hip_runtime.h>
#include <stdint.h>

typedef __attribute__((ext_vector_type(8))) short short8;
typedef __attribute__((ext_vector_type(8))) __bf16 bf16x8v;
typedef __attribute__((ext_vector_type(4))) float f32x4;

#define GLOBAL_AS __attribute__((address_space(1)))
#define LDS_AS __attribute__((address_space(3)))

__device__ __forceinline__ void gl2lds16(const void* g, void* l) {
  __builtin_amdgcn_global_load_lds((const GLOBAL_AS void*)g, (LDS_AS void*)l, 16, 0, 0);
}

__device__ __forceinline__ unsigned short f2bf(float x) {
  unsigned int u = __builtin_bit_cast(unsigned int, x);
  return (unsigned short)((u + 0x7fffu + ((u >> 16) & 1u)) >> 16);
}

__device__ __forceinline__ float bf2f(unsigned short u) {
  unsigned int v = (unsigned int)u << 16;
  return __builtin_bit_cast(float, v);
}

__device__ __forceinline__ short8 ldv8(const unsigned short* p) {
  return *(const short8*)p;
}

// --- MFMA wrapper: SFINAE-hedged against builtin operand type (short8 vs v8bf16) ---
template <typename T>
__device__ __forceinline__ auto mfma_impl(T a, T b, f32x4 c, int)
    -> decltype(__builtin_amdgcn_mfma_f32_16x16x32_bf16(a, b, c, 0, 0, 0)) {
  return __builtin_amdgcn_mfma_f32_16x16x32_bf16(a, b, c, 0, 0, 0);
}
template <typename T>
__device__ __forceinline__ f32x4 mfma_impl(T a, T b, f32x4 c, long) {
  bf16x8v aa = __builtin_bit_cast(bf16x8v, a);
  bf16x8v bb = __builtin_bit_cast(bf16x8v, b);
  return __builtin_amdgcn_mfma_f32_16x16x32_bf16(aa, bb, c, 0, 0, 0);
}
__device__ __forceinline__ f32x4 mfma16(short8 a, short8 b, f32x4 c) {
  return mfma_impl(a, b, c, 0);
}

// ---------------- cast fp32 -> bf16 (vectorized) ----------------
__global__ __launch_bounds__(256) void cast_bf16_kernel(const float* __restrict__ X,
                                                        unsigned short* __restrict__ Y,
                                                        int n4) {
  int i = blockIdx.x * 256 + threadIdx.x;
  if (i >= n4) return;
  const float4 v = ((const float4*)X)[i];
  unsigned long long pk = (unsigned long long)f2bf(v.x)
                        | ((unsigned long long)f2bf(v.y) << 16)
                        | ((unsigned long long)f2bf(v.z) << 32)
                        | ((unsigned long long)f2bf(v.w) << 48);
  ((unsigned long long*)Y)[i] = pk;
}

// ---------------- transpose + cast: W[K][N] fp32 -> Wt[N][K] bf16 ----------------
__global__ __launch_bounds__(256) void transpose_cast_kernel(const float* __restrict__ W,
                                                             unsigned short* __restrict__ Wt,
                                                             int Kd, int Nd) {
  __shared__ unsigned short tile[32][33];
  const int n0 = blockIdx.x * 32, k0 = blockIdx.y * 32;
  const int tx = threadIdx.x & 31, ty = threadIdx.x >> 5;  // 32x8
  #pragma unroll
  for (int i = 0; i < 4; ++i)
    tile[ty + i * 8][tx] = f2bf(W[(long)(k0 + ty + i * 8) * Nd + n0 + tx]);
  __syncthreads();
  #pragma unroll
  for (int i = 0; i < 4; ++i)
    Wt[(long)(n0 + ty + i * 8) * Kd + k0 + tx] = tile[tx][ty + i * 8];
}

// ---------------- GEMM: C[M,N] = A[M,K] @ Wt[N,K]^T + bias ----------------
template <int MODE>
__global__ __launch_bounds__(256) void gemm_kernel(
    const unsigned short* __restrict__ A,   // [M][K] bf16
    const unsigned short* __restrict__ Wt,  // [N][K] bf16
    const float* __restrict__ bias,         // [N]
    float* __restrict__ Cout,               // MODE1
    unsigned short* __restrict__ Qb,
    unsigned short* __restrict__ Kb,
    unsigned short* __restrict__ Vt,
    int M, int N, int K) {
  __shared__ __align__(16) unsigned short Asm[128 * 32];
  __shared__ __align__(16) unsigned short Bsm[128 * 32];
  const int tid = threadIdx.x;
  const int w = tid >> 6, l = tid & 63;
  const int m0 = blockIdx.y * 128, n0 = blockIdx.x * 128;
  const int wr = (w >> 1) * 64, wc = (w & 1) * 64;
  const int laneRow = l & 15, laneG = l >> 4;

  const f32x4 z4 = {0.f, 0.f, 0.f, 0.f};
  f32x4 acc[4][4];
  #pragma unroll
  for (int m = 0; m < 4; ++m)
    #pragma unroll
    for (int n = 0; n < 4; ++n) acc[m][n] = z4;

  const int srow = tid >> 2;
  const int scol = (tid & 3) * 8;
  const unsigned short* Ag = A + (long)(m0 + srow) * K + scol;
  const unsigned short* Bg = Wt + (long)(n0 + srow) * K + scol;
  unsigned short* AsmW = Asm + w * 512;
  unsigned short* BsmW = Bsm + w * 512;

  const int aoff = (wr + laneRow) * 32 + laneG * 8;
  const int boff = (wc + laneRow) * 32 + laneG * 8;

  for (int kt = 0; kt < K; kt += 32) {
    gl2lds16(Ag + kt, AsmW);
    gl2lds16(Ag + (long)64 * K + kt, AsmW + 2048);
    gl2lds16(Bg + kt, BsmW);
    gl2lds16(Bg + (long)64 * K + kt, BsmW + 2048);
    __syncthreads();
    short8 af[4], bfr[4];
    #pragma unroll
    for (int m = 0; m < 4; ++m) af[m] = ldv8(Asm + aoff + m * 512);
    #pragma unroll
    for (int n = 0; n < 4; ++n) bfr[n] = ldv8(Bsm + boff + n * 512);
    #pragma unroll
    for (int m = 0; m < 4; ++m)
      #pragma unroll
      for (int n = 0; n < 4; ++n)
        acc[m][n] = mfma16(af[m], bfr[n], acc[m][n]);
    __syncthreads();
  }

  #pragma unroll
  for (int m = 0; m < 4; ++m) {
    const int row_base = m0 + wr + m * 16 + laneG * 4;
    #pragma unroll
    for (int n = 0; n < 4; ++n) {
      const int col = n0 + wc + n * 16 + laneRow;
      const float bv = bias[col];
      float v0 = acc[m][n][0] + bv;
      float v1 = acc[m][n][1] + bv;
      float v2 = acc[m][n][2] + bv;
      float v3 = acc[m][n][3] + bv;
      if (MODE == 1) {
        Cout[(long)(row_base + 0) * N + col] = v0;
        Cout[(long)(row_base + 1) * N + col] = v1;
        Cout[(long)(row_base + 2) * N + col] = v2;
        Cout[(long)(row_base + 3) * N + col] = v3;
      } else {
        const int which = col >> 10;
        const int d = col & 1023;
        const int h = d >> 6, e = d & 63;
        const int bb = row_base >> 11, s = row_base & 2047;
        if (which == 2) {
          unsigned long long pk = (unsigned long long)f2bf(v0)
                                | ((unsigned long long)f2bf(v1) << 16)
                                | ((unsigned long long)f2bf(v2) << 32)
                                | ((unsigned long long)f2bf(v3) << 48);
          *(unsigned long long*)(Vt + ((long)((bb * 16 + h) * 64 + e)) * 2048 + s) = pk;
        } else {
          unsigned short* T = (which == 0) ? Qb : Kb;
          long base = ((long)(bb * 16 + h) * 2048 + s) * 64 + e;
          T[base] = f2bf(v0);
          T[base + 64] = f2bf(v1);
          T[base + 128] = f2bf(v2);
          T[base + 192] = f2bf(v3);
        }
      }
    }
  }
}

// ---------------- flash attention (causal), bf16 MFMA ----------------
// QBLK=128, 8 waves (512 thr), wave w owns q-rows [x*128+w*16, +16).
// Block px handles q-tiles px and 15-px: exactly 34 KV tiles of 64 each.
// Softmax in exp2 domain (Q pre-scaled by 0.125*log2e); rowsum via
// mfma(P, ones); defer-max (THR=8); double-buffered K/V prefetch.
__global__ __launch_bounds__(512) void attn_kernel(
    const unsigned short* __restrict__ Qb,   // [B*H][2048][64]
    const unsigned short* __restrict__ Kb,   // [B*H][2048][64]
    const unsigned short* __restrict__ Vt,   // [B*H][64][2048]
    unsigned short* __restrict__ Ao) {       // [B*2048][1024]
  __shared__ __align__(16) unsigned short Ksm[2][64 * 64];
  __shared__ __align__(16) unsigned short Vsm[2][64 * 64];
  __shared__ __align__(16) unsigned short Psm[8][16][72];  // per-wave [q][key], padded

  const int tid = threadIdx.x;
  const int w = tid >> 6, l = tid & 63;
  const int px = blockIdx.x, y = blockIdx.y;
  const int laneRow = l & 15, g = l >> 4;
  const unsigned short* Qh = Qb + (long)y * (2048 * 64);
  const unsigned short* Kh = Kb + (long)y * (2048 * 64);
  const unsigned short* Vh = Vt + (long)y * (64 * 2048);

  const int srow = tid >> 3;                       // 0..63
  const int sxor = ((tid & 7) ^ (srow & 7)) * 8;   // XOR-swizzled source col
  const int b = y >> 4, h = y & 15;
  const f32x4 z4 = {0.f, 0.f, 0.f, 0.f};
  short8 ones8;
  #pragma unroll
  for (int j = 0; j < 8; ++j) ones8[j] = (short)0x3F80;  // bf16 1.0

  auto STAGE = [&](int buf, int kt) {
    gl2lds16(Kh + (long)kt * 4096 + srow * 64 + sxor, &Ksm[buf][w * 512]);
    gl2lds16(Vh + kt * 64 + (long)srow * 2048 + sxor, &Vsm[buf][w * 512]);
  };

  for (int pass = 0; pass < 2; ++pass) {
    const int x = pass ? (15 - px) : px;
    const int q0 = x * 128;
    const int qlo = w * 16;  // wave's first q-row within tile

    // Q fragments, pre-scaled by 0.125 * log2(e) (exp2-domain softmax)
    const float QS = 0.18033688011112042f;
    short8 qf[2];
    {
      short8 r0 = ldv8(Qh + (q0 + qlo + laneRow) * 64 + g * 8);
      short8 r1 = ldv8(Qh + (q0 + qlo + laneRow) * 64 + 32 + g * 8);
      #pragma unroll
      for (int j = 0; j < 8; ++j) {
        qf[0][j] = (short)f2bf(bf2f((unsigned short)r0[j]) * QS);
        qf[1][j] = (short)f2bf(bf2f((unsigned short)r1[j]) * QS);
      }
    }

    float mr[4] = {-1e30f, -1e30f, -1e30f, -1e30f};
    float lr[4] = {0.f, 0.f, 0.f, 0.f};
    f32x4 o[4];
    #pragma unroll
    for (int i = 0; i < 4; ++i) o[i] = z4;

    const int nkt = 2 * x + 2;
    int cur = 0;
    STAGE(0, 0);
    asm volatile("s_waitcnt vmcnt(0)" ::: "memory");
    __builtin_amdgcn_s_barrier();

    for (int kt = 0; kt < nkt; ++kt) {
      if (kt + 1 < nkt) STAGE(cur ^ 1, kt + 1);  // prefetch next tile

      const int keybase = kt * 64 - q0;  // key index relative to tile base
      const bool fullskip = keybase > qlo + 15;

      if (!fullskip) {
        // S = Q K^T (pre-scaled, log2 domain)
        f32x4 sc[4];
        __builtin_amdgcn_s_setprio(1);
        #pragma unroll
        for (int n = 0; n < 4; ++n) {
          const int krow = n * 16 + laneRow;
          short8 b0 = ldv8(&Ksm[cur][krow * 64 + ((g ^ (krow & 7)) * 8)]);
          short8 b1 = ldv8(&Ksm[cur][krow * 64 + (((g + 4) ^ (krow & 7)) * 8)]);
          f32x4 a = mfma16(qf[0], b0, z4);
          sc[n] = mfma16(qf[1], b1, a);
        }
        __builtin_amdgcn_s_setprio(0);

        // causal mask (tiles touching the diagonal only)
        if (keybase + 63 > qlo) {
          #pragma unroll
          for (int n = 0; n < 4; ++n) {
            const int key = keybase + n * 16 + laneRow;
            #pragma unroll
            for (int r = 0; r < 4; ++r)
              if (key > qlo + g * 4 + r) sc[n][r] = -1e9f;
          }
        }

        // per-row tile max (rows live across 16-lane groups)
        float pm[4];
        #pragma unroll
        for (int r = 0; r < 4; ++r) {
          float v = fmaxf(fmaxf(sc[0][r], sc[1][r]), fmaxf(sc[2][r], sc[3][r]));
          v = fmaxf(v, __shfl_xor(v, 1));
          v = fmaxf(v, __shfl_xor(v, 2));
          v = fmaxf(v, __shfl_xor(v, 4));
          v = fmaxf(v, __shfl_xor(v, 8));
          pm[r] = v;
        }

        // defer-max: skip rescale when max growth <= 8 (P bounded by 2^8)
        int cnd = (pm[0] <= mr[0] + 8.f) & (pm[1] <= mr[1] + 8.f) &
                  (pm[2] <= mr[2] + 8.f) & (pm[3] <= mr[3] + 8.f);
        const bool defer = __all(cnd);
        float so_[4];
        if (!defer) {
          #pragma unroll
          for (int r = 0; r < 4; ++r) {
            float mn = fmaxf(mr[r], pm[r]);
            so_[r] = exp2f(mr[r] - mn);
            mr[r] = mn;
          }
        }

        // P = exp2(S - m)
        #pragma unroll
        for (int n = 0; n < 4; ++n)
          #pragma unroll
          for (int r = 0; r < 4; ++r)
            sc[n][r] = exp2f(sc[n][r] - mr[r]);

        if (!defer) {
          #pragma unroll
          for (int n2 = 0; n2 < 4; ++n2) {
            o[n2][0] *= so_[0];
            o[n2][1] *= so_[1];
            o[n2][2] *= so_[2];
            o[n2][3] *= so_[3];
          }
        }

        // P -> LDS (per-wave, padded) layout [q][key]
        #pragma unroll
        for (int n = 0; n < 4; ++n)
          #pragma unroll
          for (int r = 0; r < 4; ++r)
            Psm[w][g * 4 + r][n * 16 + laneRow] = f2bf(sc[n][r]);
        asm volatile("s_waitcnt lgkmcnt(0)" ::: "memory");

        // O += P V ; rowsum via mfma(P, ones)
        f32x4 rs = z4;
        #pragma unroll
        for (int kk = 0; kk < 2; ++kk) {
          short8 pf = ldv8(&Psm[w][laneRow][kk * 32 + g * 8]);
          __builtin_amdgcn_s_setprio(1);
          #pragma unroll
          for (int n2 = 0; n2 < 4; ++n2) {
            const int vrow = n2 * 16 + laneRow;
            short8 vf = ldv8(&Vsm[cur][vrow * 64 + (((g + kk * 4) ^ (vrow & 7)) * 8)]);
            o[n2] = mfma16(pf, vf, o[n2]);
          }
          rs = mfma16(pf, ones8, rs);
          __builtin_amdgcn_s_setprio(0);
        }

        if (defer) {
          #pragma unroll
          for (int r = 0; r < 4; ++r) lr[r] += rs[r];
        } else {
          #pragma unroll
          for (int r = 0; r < 4; ++r) lr[r] = lr[r] * so_[r] + rs[r];
        }
      }

      asm volatile("s_waitcnt vmcnt(0)" ::: "memory");
      __builtin_amdgcn_s_barrier();
      cur ^= 1;
    }

    // epilogue: O / l
    #pragma unroll
    for (int n2 = 0; n2 < 4; ++n2) {
      #pragma unroll
      for (int r = 0; r < 4; ++r) {
        float v = o[n2][r] / lr[r];
        long row = (long)b * 2048 + q0 + qlo + g * 4 + r;
        Ao[row * 1024 + h * 64 + n2 * 16 + laneRow] = f2bf(v);
      }
    }
  }
}

// ---------------- launch ----------------
extern "C" void kernel_launch(void* const* d_in, const int* in_sizes, int n_in,
                              void* d_out, int out_size, void* d_ws, size_t ws_size,
                              hipStream_t stream) {
  const float* hs = (const float*)d_in[0];      // [4,2048,1024]
  const float* W_attn = (const float*)d_in[1];  // [1024,3072]
  const float* b_attn = (const float*)d_in[2];  // [3072]
  const float* W_proj = (const float*)d_in[3];  // [1024,1024]
  const float* b_proj = (const float*)d_in[4];  // [1024]
  float* out = (float*)d_out;

  const size_t SZ_HS = 16777216;  // 8192*1024*2
  const size_t SZ_WA = 6291456;   // 3072*1024*2
  const size_t SZ_WP = 2097152;   // 1024*1024*2
  const size_t SZ_T = 16777216;   // Q / K / Vt / Ao each
  if (ws_size < SZ_HS + SZ_WA + SZ_WP + 4 * SZ_T) return;

  char* p = (char*)d_ws;
  unsigned short* hs_bf = (unsigned short*)p; p += SZ_HS;
  unsigned short* WtA = (unsigned short*)p;   p += SZ_WA;
  unsigned short* WtP = (unsigned short*)p;   p += SZ_WP;
  unsigned short* Qb = (unsigned short*)p;    p += SZ_T;
  unsigned short* Kb = (unsigned short*)p;    p += SZ_T;
  unsigned short* Vt = (unsigned short*)p;    p += SZ_T;
  unsigned short* Ao = (unsigned short*)p;    p += SZ_T;

  cast_bf16_kernel<<<8192, 256, 0, stream>>>(hs, hs_bf, 8192 * 1024 / 4);
  transpose_cast_kernel<<<dim3(96, 32), 256, 0, stream>>>(W_attn, WtA, 1024, 3072);
  transpose_cast_kernel<<<dim3(32, 32), 256, 0, stream>>>(W_proj, WtP, 1024, 1024);
  gemm_kernel<0><<<dim3(24, 64), 256, 0, stream>>>(hs_bf, WtA, b_attn, nullptr, Qb, Kb, Vt,
                                                   8192, 3072, 1024);
  attn_kernel<<<dim3(8, 64), 512, 0, stream>>>(Qb, Kb, Vt, Ao);
  gemm_kernel<1><<<dim3(8, 64), 256, 0, stream>>>(Ao, WtP, b_proj, out, nullptr, nullptr, nullptr,
                                                  8192, 1024, 1024);
}